// Round 6
// baseline (370.173 us; speedup 1.0000x reference)
//
#include <hip/hip_runtime.h>

typedef __attribute__((ext_vector_type(8))) short short8;
typedef __attribute__((ext_vector_type(4))) float f32x4;
typedef unsigned short u16;

#define T_SEQ 2048
#define C_DIM 2048

static __device__ __forceinline__ u16 f2bf(float f){
  unsigned u = __float_as_uint(f);
  u = (u + 0x7fffu + ((u >> 16) & 1u)) >> 16;
  return (u16)u;
}

__global__ void cvt_kernel(const float* __restrict__ in, u16* __restrict__ out, int n4){
  int idx = blockIdx.x * blockDim.x + threadIdx.x;
  int stride = gridDim.x * blockDim.x;
  for (int i = idx; i < n4; i += stride){
    float4 v = ((const float4*)in)[i];
    ushort4 o;
    o.x = f2bf(v.x); o.y = f2bf(v.y); o.z = f2bf(v.z); o.w = f2bf(v.w);
    ((ushort4*)out)[i] = o;
  }
}

__device__ __forceinline__ void gl_lds16(const void* g, void* l){
  __builtin_amdgcn_global_load_lds(
      (const __attribute__((address_space(1))) unsigned int*)g,
      (__attribute__((address_space(3))) unsigned int*)l,
      16, 0, 0);
}

// C = A[M,K] * B[N,K]^T, bf16 in. Tile 256x128 (BM=256, BN=128), BK=64,
// 8 waves (4M x 2N), 64x64 per wave. Triple-buffered LDS, counted vmcnt(6),
// 4 phases per K-tile, XOR-swizzled LDS (elem ^= (row&7)<<3), pre-swizzled
// global source for linear gl_lds dest (rule: both-sides-or-neither).
// MODE 0: plain write to C[M,N] (LD=N). MODE 1: qkv-split (cols<4096 -> qk
// LD 4096; cols>=4096 -> VT[b][h][d][t]).
template<int MODE, typename OUT>
__global__ __launch_bounds__(512, 2) void gemm_bt(const u16* __restrict__ A,
                                                  const u16* __restrict__ B,
                                                  OUT* __restrict__ C,
                                                  u16* __restrict__ VT,
                                                  int M, int N, int K){
  __shared__ __align__(16) u16 lA[3][256*64];   // 96 KB
  __shared__ __align__(16) u16 lB[3][128*64];   // 48 KB
  const int tid  = threadIdx.x;
  const int lane = tid & 63;
  const int r16  = lane & 15;
  const int g4   = lane >> 4;
  const int wave = tid >> 6;          // 0..7
  const int wm = wave >> 1, wn = wave & 1;
  const int lrow = lane >> 3;                     // 0..7
  const int lcol = ((lane & 7) ^ lrow) << 3;      // inverse-swizzled src elem

  // bijective XCD swizzle (nwg%8==0); within an XCD, m-tiles walk fastest
  const int nwg = gridDim.x * gridDim.y;
  const int idl = blockIdx.y * gridDim.x + blockIdx.x;
  const int wg  = (idl & 7) * (nwg >> 3) + (idl >> 3);
  const int bx  = wg / gridDim.y, by = wg % gridDim.y;
  const int m0 = by * 256, n0 = bx * 128;

  f32x4 acc[4][4] = {};
  const int nt = K >> 6;

  auto stageA = [&](int sb, int t, int c){
    const int row0 = (wave*4 + c)*8;   // wave-uniform, 8 rows per instr
    gl_lds16(&A[(size_t)(m0 + row0 + lrow)*K + t*64 + lcol], &lA[sb][row0*64]);
  };
  auto stageB = [&](int sb, int t, int c){
    const int row0 = (wave*2 + c)*8;
    gl_lds16(&B[(size_t)(n0 + row0 + lrow)*K + t*64 + lcol], &lB[sb][row0*64]);
  };

  // prologue: stage tiles 0 and 1 (12 loads outstanding per thread)
  stageA(0,0,0); stageA(0,0,1); stageA(0,0,2); stageA(0,0,3);
  stageB(0,0,0); stageB(0,0,1);
  stageA(1,1,0); stageA(1,1,1); stageA(1,1,2); stageA(1,1,3);
  stageB(1,1,0); stageB(1,1,1);

  for (int t = 0; t < nt; ++t){
    const int cb = t % 3;
    const int sb = (t + 2) % 3;
    // wait: tile t's 6 loads retired (t+1's 6 may stay in flight)
    if (t + 1 < nt) asm volatile("s_waitcnt vmcnt(6)" ::: "memory");
    else            asm volatile("s_waitcnt vmcnt(0)" ::: "memory");
    __builtin_amdgcn_s_barrier();

    #pragma unroll
    for (int p = 0; p < 4; ++p){
      const int pm = p >> 1, pn = p & 1;   // C-quadrant of the wave's 64x64
      short8 af[2][2], bf[2][2];
      #pragma unroll
      for (int ii=0; ii<2; ii++){
        const int R = wm*64 + (pm*2+ii)*16 + r16;
        #pragma unroll
        for (int ks=0; ks<2; ks++)
          af[ii][ks] = *(const short8*)&lA[cb][R*64 + ((g4*8 + ks*32) ^ ((R&7)<<3))];
      }
      #pragma unroll
      for (int jj=0; jj<2; jj++){
        const int R = wn*64 + (pn*2+jj)*16 + r16;
        #pragma unroll
        for (int ks=0; ks<2; ks++)
          bf[jj][ks] = *(const short8*)&lB[cb][R*64 + ((g4*8 + ks*32) ^ ((R&7)<<3))];
      }
      if (t + 2 < nt){   // spread tile-(t+2) staging across phases 0-2
        if (p == 0){ stageA(sb, t+2, 0); stageA(sb, t+2, 1); }
        else if (p == 1){ stageA(sb, t+2, 2); stageA(sb, t+2, 3); }
        else if (p == 2){ stageB(sb, t+2, 0); stageB(sb, t+2, 1); }
      }
      __builtin_amdgcn_s_barrier();
      __builtin_amdgcn_s_setprio(1);
      #pragma unroll
      for (int ii=0; ii<2; ii++)
        #pragma unroll
        for (int jj=0; jj<2; jj++)
          #pragma unroll
          for (int ks=0; ks<2; ks++)
            acc[pm*2+ii][pn*2+jj] = __builtin_amdgcn_mfma_f32_16x16x32_bf16(
                af[ii][ks], bf[jj][ks], acc[pm*2+ii][pn*2+jj], 0,0,0);
      __builtin_amdgcn_s_setprio(0);
      __builtin_amdgcn_s_barrier();
    }
  }

  if (MODE == 1 && n0 >= 4096){
    // V third -> VT[b][h][d][t], 8B packed store (4 consecutive t per lane)
    #pragma unroll
    for (int i=0;i<4;i++){
      const int m = m0 + wm*64 + i*16 + g4*4;
      const int bb = m >> 11, tt = m & 2047;
      #pragma unroll
      for (int j=0;j<4;j++){
        const int cv = n0 + wn*64 + j*16 + r16 - 4096;
        const int h = cv >> 7, dl = cv & 127;
        ushort4 pack;
        pack.x = f2bf(acc[i][j][0]); pack.y = f2bf(acc[i][j][1]);
        pack.z = f2bf(acc[i][j][2]); pack.w = f2bf(acc[i][j][3]);
        *(ushort4*)&VT[(size_t)((bb<<4) + h)*262144 + (size_t)dl*2048 + tt] = pack;
      }
    }
  } else {
    const int ldc = (MODE == 1) ? 4096 : N;
    #pragma unroll
    for (int i=0;i<4;i++){
      const int row = m0 + wm*64 + i*16 + g4*4;
      #pragma unroll
      for (int j=0;j<4;j++){
        const int col = n0 + wn*64 + j*16 + r16;
        #pragma unroll
        for (int r=0;r<4;r++){
          float v = acc[i][j][r];
          if constexpr (sizeof(OUT)==2) C[(size_t)(row+r)*ldc + col] = (OUT)f2bf(v);
          else                          C[(size_t)(row+r)*ldc + col] = (OUT)v;
        }
      }
    }
  }
}

// Flash attention, QBLK=128, KVBLK=64, 2-phase gl_lds pipeline.
// qk: [B*T][4096] (Q cols 0..2047, K cols 2048..4095), vt: [B*16+h][128][2048].
__global__ __launch_bounds__(256) void attn_kernel(const u16* __restrict__ qk,
                                                   const u16* __restrict__ vt,
                                                   u16* __restrict__ y){
  __shared__ __align__(16) u16 Kl[2][64*128];  // [kv][d], XOR-swizzled content
  __shared__ __align__(16) u16 Vl[2][128*64];  // [d][kv], XOR-swizzled content
  __shared__ __align__(16) u16 Pl[4][32*64];   // per-wave P, XOR-swizzled

  const int tid = threadIdx.x, lane = tid & 63, wave = tid >> 6;
  const int r16 = lane & 15, g4 = lane >> 4;

  const int id = blockIdx.x;            // 0..511
  const int xk = id & 7,  kk = id >> 3; // xcd, 0..63
  const int bh = 4*xk + (kk & 3);
  const int v5 = kk >> 2;               // 0..15
  const int qt = (v5 < 8) ? v5 : (23 - v5);

  const int b = bh >> 4, h = bh & 15;
  const int qcol = h*128, kcol = 2048 + h*128;
  const u16* vhead = vt + (size_t)bh * 262144;
  const float scale = 0.08838834764831845f;  // 1/sqrt(128)

  short8 qf[2][4];
  #pragma unroll
  for (int i=0;i<2;i++){
    const u16* qp = qk + (size_t)(b*T_SEQ + qt*128 + wave*32 + i*16 + r16)*4096 + qcol;
    #pragma unroll
    for (int c=0;c<4;c++) qf[i][c] = *(const short8*)&qp[g4*8 + c*32];
  }

  float mrow[2][4], lrow[2][4];
  #pragma unroll
  for (int i=0;i<2;i++)
    #pragma unroll
    for (int r=0;r<4;r++){ mrow[i][r] = -1e30f; lrow[i][r] = 0.f; }
  f32x4 o[2][8] = {};

  const int nt = 2*qt + 2;

  auto stage = [&](int sbuf, int t){
    const size_t kbase = (size_t)(b*T_SEQ + t*64)*4096 + kcol;
    #pragma unroll
    for (int c=0;c<4;c++){
      const int row0 = wave*16 + c*4;       // wave-uniform
      const int row  = row0 + g4;
      gl_lds16(&qk[kbase + (size_t)row*4096 + ((r16*8) ^ ((row&7)<<3))],
               &Kl[sbuf][row0*128]);
    }
    const int t0 = t*64;
    #pragma unroll
    for (int c=0;c<4;c++){
      const int idx = wave*4 + c;           // 0..15, wave-uniform
      const int d   = idx*8 + (lane>>3);
      const int j8  = (lane&7)*8;
      gl_lds16(&vhead[(size_t)d*2048 + t0 + (j8 ^ ((d&7)<<3))],
               &Vl[sbuf][idx*512]);
    }
  };

  stage(0, 0);
  int cur = 0;

  for (int t = 0; t < nt; ++t){
    __syncthreads();           // drains vmcnt -> buf[cur] ready; prev reads done
    if (t + 1 < nt) stage(cur^1, t+1);

    // ---- S = Q K^T : per wave 32q x 64kv
    float smat[2][4][4];
    #pragma unroll
    for (int cc=0;cc<4;cc++){
      const int krow = cc*16 + r16;
      const int sw = (krow & 7) << 3;
      short8 kf[4];
      #pragma unroll
      for (int dc=0;dc<4;dc++)
        kf[dc] = *(const short8*)&Kl[cur][krow*128 + ((g4*8 + dc*32) ^ sw)];
      #pragma unroll
      for (int i=0;i<2;i++){
        f32x4 sv = {0.f,0.f,0.f,0.f};
        #pragma unroll
        for (int dc=0;dc<4;dc++)
          sv = __builtin_amdgcn_mfma_f32_16x16x32_bf16(qf[i][dc], kf[dc], sv, 0,0,0);
        #pragma unroll
        for (int rr=0;rr<4;rr++) smat[i][cc][rr] = sv[rr] * scale;
      }
    }
    if (t >= 2*qt){  // diagonal region (uniform branch)
      #pragma unroll
      for (int cc=0;cc<4;cc++){
        const int kvl = (t - 2*qt)*64 + cc*16 + r16;
        #pragma unroll
        for (int i=0;i<2;i++)
          #pragma unroll
          for (int rr=0;rr<4;rr++){
            const int qi = wave*32 + i*16 + g4*4 + rr;
            if (kvl > qi) smat[i][cc][rr] = -1e30f;
          }
      }
    }

    // ---- online softmax (rows on 16-lane groups)
    float corr[2][4];
    #pragma unroll
    for (int i=0;i<2;i++)
      #pragma unroll
      for (int rr=0;rr<4;rr++){
        float pm = fmaxf(fmaxf(smat[i][0][rr], smat[i][1][rr]),
                         fmaxf(smat[i][2][rr], smat[i][3][rr]));
        #pragma unroll
        for (int off=1; off<16; off<<=1) pm = fmaxf(pm, __shfl_xor(pm, off, 64));
        const float mnew = fmaxf(mrow[i][rr], pm);
        corr[i][rr] = __expf(mrow[i][rr] - mnew);
        float s0 = 0.f;
        #pragma unroll
        for (int cc=0;cc<4;cc++){
          const float p = __expf(smat[i][cc][rr] - mnew);
          smat[i][cc][rr] = p;
          s0 += p;
        }
        #pragma unroll
        for (int off=1; off<16; off<<=1) s0 += __shfl_xor(s0, off, 64);
        lrow[i][rr] = lrow[i][rr]*corr[i][rr] + s0;
        mrow[i][rr] = mnew;
      }
    #pragma unroll
    for (int i=0;i<2;i++)
      #pragma unroll
      for (int n=0;n<8;n++)
        #pragma unroll
        for (int rr=0;rr<4;rr++)
          o[i][n][rr] *= corr[i][rr];

    // ---- P -> LDS (bf16), wave-local
    #pragma unroll
    for (int i=0;i<2;i++)
      #pragma unroll
      for (int cc=0;cc<4;cc++)
        #pragma unroll
        for (int rr=0;rr<4;rr++){
          const int qr = i*16 + g4*4 + rr;
          Pl[wave][qr*64 + ((cc*16 + r16) ^ ((qr&7)<<3))] = f2bf(smat[i][cc][rr]);
        }
    asm volatile("s_waitcnt lgkmcnt(0)" ::: "memory");

    short8 pf[2][2];
    #pragma unroll
    for (int i=0;i<2;i++){
      const int qr = i*16 + r16;
      const int sw = (qr & 7) << 3;
      pf[i][0] = *(const short8*)&Pl[wave][qr*64 + ((g4*8)      ^ sw)];
      pf[i][1] = *(const short8*)&Pl[wave][qr*64 + ((g4*8 + 32) ^ sw)];
    }
    #pragma unroll
    for (int n=0;n<8;n++){
      const int vr = n*16 + r16;
      const int sw = (vr & 7) << 3;
      short8 vf0 = *(const short8*)&Vl[cur][vr*64 + ((g4*8)      ^ sw)];
      short8 vf1 = *(const short8*)&Vl[cur][vr*64 + ((g4*8 + 32) ^ sw)];
      #pragma unroll
      for (int i=0;i<2;i++){
        o[i][n] = __builtin_amdgcn_mfma_f32_16x16x32_bf16(pf[i][0], vf0, o[i][n], 0,0,0);
        o[i][n] = __builtin_amdgcn_mfma_f32_16x16x32_bf16(pf[i][1], vf1, o[i][n], 0,0,0);
      }
    }
    cur ^= 1;
  }

  #pragma unroll
  for (int i=0;i<2;i++){
    const size_t yr0 = (size_t)(b*T_SEQ + qt*128 + wave*32 + i*16 + g4*4) * C_DIM + h*128;
    #pragma unroll
    for (int n=0;n<8;n++)
      #pragma unroll
      for (int rr=0;rr<4;rr++){
        const float v = o[i][n][rr] / lrow[i][rr];
        y[yr0 + (size_t)rr*C_DIM + n*16 + r16] = f2bf(v);
      }
  }
}

extern "C" void kernel_launch(void* const* d_in, const int* in_sizes, int n_in,
                              void* d_out, int out_size, void* d_ws, size_t ws_size,
                              hipStream_t stream){
  const float* x  = (const float*)d_in[0];
  const float* wa = (const float*)d_in[1];
  const float* wp = (const float*)d_in[2];
  float* out = (float*)d_out;

  u16* ws  = (u16*)d_ws;
  u16* xb  = ws;                 //  8,388,608 elems (x bf16) — reused as yb later
  u16* wab = xb  + 8388608;      // 12,582,912 elems (w_attn bf16)
  u16* wpb = wab + 12582912;     //  4,194,304 elems (w_proj bf16)
  u16* qk  = wpb + 4194304;      // 16,777,216 elems ([4096][4096] Q|K)
  u16* vt  = qk  + 16777216;     //  8,388,608 elems ([32][128][2048] V^T)
  u16* yb  = xb;                 // alias: x dead after GEMM1

  hipLaunchKernelGGL(cvt_kernel, dim3(1024), dim3(256), 0, stream, x,  xb,  8388608/4);
  hipLaunchKernelGGL(cvt_kernel, dim3(1024), dim3(256), 0, stream, wa, wab, 12582912/4);
  hipLaunchKernelGGL(cvt_kernel, dim3(1024), dim3(256), 0, stream, wp, wpb, 4194304/4);

  // qkv projection with V-split epilogue: grid 48 n-tiles(128) x 16 m-tiles(256)
  hipLaunchKernelGGL((gemm_bt<1,u16>),   dim3(48,16), dim3(512), 0, stream,
                     xb, wab, qk, vt, 4096, 6144, 2048);
  hipLaunchKernelGGL(attn_kernel,        dim3(512),  dim3(256), 0, stream,
                     qk, vt, yb);
  // out projection: grid 16 x 16 = 256 blocks (exactly 1 block/CU)
  hipLaunchKernelGGL((gemm_bt<0,float>), dim3(16,16), dim3(512), 0, stream,
                     yb, wpb, out, (u16*)nullptr, 4096, 2048, 2048);
}

// Round 7
// 322.389 us; speedup vs baseline: 1.1482x; 1.1482x over previous
//
#include <hip/hip_runtime.h>

typedef __attribute__((ext_vector_type(8))) short short8;
typedef __attribute__((ext_vector_type(4))) float f32x4;
typedef unsigned short u16;

#define T_SEQ 2048
#define C_DIM 2048

static __device__ __forceinline__ u16 f2bf(float f){
  unsigned u = __float_as_uint(f);
  u = (u + 0x7fffu + ((u >> 16) & 1u)) >> 16;
  return (u16)u;
}

__global__ void cvt_kernel(const float* __restrict__ in, u16* __restrict__ out, int n4){
  int idx = blockIdx.x * blockDim.x + threadIdx.x;
  int stride = gridDim.x * blockDim.x;
  for (int i = idx; i < n4; i += stride){
    float4 v = ((const float4*)in)[i];
    ushort4 o;
    o.x = f2bf(v.x); o.y = f2bf(v.y); o.z = f2bf(v.z); o.w = f2bf(v.w);
    ((ushort4*)out)[i] = o;
  }
}

__device__ __forceinline__ void gl_lds16(const void* g, void* l){
  __builtin_amdgcn_global_load_lds(
      (const __attribute__((address_space(1))) unsigned int*)g,
      (__attribute__((address_space(3))) unsigned int*)l,
      16, 0, 0);
}

// ---------------- 256x256 deep-pipelined GEMM (bottleneck kernel) -----------
// C = A[M,K]*B[N,K]^T. BM=BN=256, BK=32, 8 waves (2M x 4N), 128x64 per wave.
// Triple-buffered LDS (96KB), counted vmcnt(4) at tile boundary (stage runs
// 2 tiles ahead), 2 phases/K-tile x 16 MFMA, B-frags reg-cached, XOR swizzle
// (elem ^= (row&3)<<3) with inverse-swizzled global source (linear gl_lds dest).
// MODE 0: plain C[M,N]. MODE 1: qkv-split (cols<4096 -> qk LD4096; else VT).
template<int MODE, typename OUT>
__global__ __launch_bounds__(512, 2) void gemm256(const u16* __restrict__ A,
                                                  const u16* __restrict__ B,
                                                  OUT* __restrict__ C,
                                                  u16* __restrict__ VT,
                                                  int M, int N, int K){
  __shared__ __align__(16) u16 lA[3][256*32];   // 48 KB
  __shared__ __align__(16) u16 lB[3][256*32];   // 48 KB
  const int tid  = threadIdx.x;
  const int lane = tid & 63;
  const int r16  = lane & 15;
  const int g4   = lane >> 4;
  const int wave = tid >> 6;            // 0..7
  const int wm = wave >> 2, wn = wave & 3;   // 2M x 4N

  const int nwg = gridDim.x * gridDim.y;
  const int idl = blockIdx.y * gridDim.x + blockIdx.x;
  const int wg  = (idl & 7) * (nwg >> 3) + (idl >> 3);
  const int bx  = wg / gridDim.y, by = wg % gridDim.y;
  const int m0 = by * 256, n0 = bx * 256;

  f32x4 acc[8][4] = {};
  const int nt = K >> 5;

  const int srowl = lane >> 2;                 // 0..15 within instr
  auto stageA = [&](int sb, int t, int c){
    const int row0 = wave*32 + c*16;           // wave-uniform
    const int row  = row0 + srowl;
    const int col  = ((lane & 3) << 3) ^ ((row & 3) << 3);
    gl_lds16(&A[(size_t)(m0 + row)*K + t*32 + col], &lA[sb][row0*32]);
  };
  auto stageB = [&](int sb, int t, int c){
    const int row0 = wave*32 + c*16;
    const int row  = row0 + srowl;
    const int col  = ((lane & 3) << 3) ^ ((row & 3) << 3);
    gl_lds16(&B[(size_t)(n0 + row)*K + t*32 + col], &lB[sb][row0*32]);
  };

  // prologue: tiles 0 and 1 fully staged (8 instrs in flight)
  stageA(0,0,0); stageA(0,0,1); stageB(0,0,0); stageB(0,0,1);
  stageA(1,1,0); stageA(1,1,1); stageB(1,1,0); stageB(1,1,1);

  for (int t = 0; t < nt; ++t){
    const u16* bufA = lA[t % 3];
    const u16* bufB = lB[t % 3];
    const int sb = (t + 2) % 3;
    if (t < nt - 1) asm volatile("s_waitcnt vmcnt(4)" ::: "memory");
    else            asm volatile("s_waitcnt vmcnt(0)" ::: "memory");
    __builtin_amdgcn_s_barrier();

    short8 af[4], bfv[4];
    // ---- phase 0: wave rows 0..63, all 64 cols, K=32
    #pragma unroll
    for (int i=0;i<4;i++){
      const int R = wm*128 + i*16 + r16;
      af[i] = *(const short8*)&bufA[R*32 + ((g4*8) ^ ((R&3)<<3))];
    }
    #pragma unroll
    for (int j=0;j<4;j++){
      const int R = wn*64 + j*16 + r16;
      bfv[j] = *(const short8*)&bufB[R*32 + ((g4*8) ^ ((R&3)<<3))];
    }
    if (t + 2 < nt){ stageA(sb, t+2, 0); stageA(sb, t+2, 1); }
    asm volatile("s_waitcnt lgkmcnt(0)" ::: "memory");
    __builtin_amdgcn_sched_barrier(0);
    __builtin_amdgcn_s_setprio(1);
    #pragma unroll
    for (int i=0;i<4;i++)
      #pragma unroll
      for (int j=0;j<4;j++)
        acc[i][j] = __builtin_amdgcn_mfma_f32_16x16x32_bf16(af[i], bfv[j], acc[i][j], 0,0,0);
    __builtin_amdgcn_s_setprio(0);
    __builtin_amdgcn_s_barrier();

    // ---- phase 1: wave rows 64..127 (B-frags reused from registers)
    #pragma unroll
    for (int i=0;i<4;i++){
      const int R = wm*128 + 64 + i*16 + r16;
      af[i] = *(const short8*)&bufA[R*32 + ((g4*8) ^ ((R&3)<<3))];
    }
    if (t + 2 < nt){ stageB(sb, t+2, 0); stageB(sb, t+2, 1); }
    asm volatile("s_waitcnt lgkmcnt(0)" ::: "memory");
    __builtin_amdgcn_sched_barrier(0);
    __builtin_amdgcn_s_setprio(1);
    #pragma unroll
    for (int i=0;i<4;i++)
      #pragma unroll
      for (int j=0;j<4;j++)
        acc[4+i][j] = __builtin_amdgcn_mfma_f32_16x16x32_bf16(af[i], bfv[j], acc[4+i][j], 0,0,0);
    __builtin_amdgcn_s_setprio(0);
  }

  if (MODE == 1 && n0 >= 4096){
    #pragma unroll
    for (int i=0;i<8;i++){
      const int m = m0 + wm*128 + i*16 + g4*4;
      const int bb = m >> 11, tt = m & 2047;
      #pragma unroll
      for (int j=0;j<4;j++){
        const int cv = n0 + wn*64 + j*16 + r16 - 4096;
        const int h = cv >> 7, dl = cv & 127;
        ushort4 pack;
        pack.x = f2bf(acc[i][j][0]); pack.y = f2bf(acc[i][j][1]);
        pack.z = f2bf(acc[i][j][2]); pack.w = f2bf(acc[i][j][3]);
        *(ushort4*)&VT[(size_t)((bb<<4) + h)*262144 + (size_t)dl*2048 + tt] = pack;
      }
    }
  } else {
    const int ldc = (MODE == 1) ? 4096 : N;
    #pragma unroll
    for (int i=0;i<8;i++){
      const int row = m0 + wm*128 + i*16 + g4*4;
      #pragma unroll
      for (int j=0;j<4;j++){
        const int col = n0 + wn*64 + j*16 + r16;
        #pragma unroll
        for (int r=0;r<4;r++){
          float v = acc[i][j][r];
          if constexpr (sizeof(OUT)==2) C[(size_t)(row+r)*ldc + col] = (OUT)f2bf(v);
          else                          C[(size_t)(row+r)*ldc + col] = (OUT)v;
        }
      }
    }
  }
}

// ---------------- 128x128 m97-style GEMM (known-good, for out-proj) ---------
__global__ __launch_bounds__(256) void gemm128(const u16* __restrict__ A,
                                               const u16* __restrict__ B,
                                               float* __restrict__ C,
                                               int M, int N, int K){
  __shared__ __align__(16) u16 lA[2][128*32];
  __shared__ __align__(16) u16 lB[2][128*32];
  const int tid  = threadIdx.x;
  const int lane = tid & 63;
  const int r16  = lane & 15;
  const int g4   = lane >> 4;
  const int wave = tid >> 6;
  const int wr = (wave >> 1) * 64, wc = (wave & 1) * 64;

  const int nwg = gridDim.x * gridDim.y;
  const int idl = blockIdx.y * gridDim.x + blockIdx.x;
  const int wg  = (idl & 7) * (nwg >> 3) + (idl >> 3);
  const int bx  = wg / gridDim.y, by = wg % gridDim.y;
  const int m0 = by * 128, n0 = bx * 128;

  const int srow = tid >> 2;
  const int scol = (tid & 3) << 3;

  f32x4 acc[4][4] = {};
  const int nk = K >> 5;
  int buf = 0;

  gl_lds16(&A[(size_t)(m0 + srow)*K + scol],      &lA[0][srow*32 + scol]);
  gl_lds16(&A[(size_t)(m0 + 64 + srow)*K + scol], &lA[0][(64+srow)*32 + scol]);
  gl_lds16(&B[(size_t)(n0 + srow)*K + scol],      &lB[0][srow*32 + scol]);
  gl_lds16(&B[(size_t)(n0 + 64 + srow)*K + scol], &lB[0][(64+srow)*32 + scol]);

  for (int kt = 0; kt < nk; ++kt){
    __syncthreads();
    if (kt + 1 < nk){
      const int k0 = (kt + 1) << 5;
      gl_lds16(&A[(size_t)(m0 + srow)*K + k0 + scol],      &lA[buf^1][srow*32 + scol]);
      gl_lds16(&A[(size_t)(m0 + 64 + srow)*K + k0 + scol], &lA[buf^1][(64+srow)*32 + scol]);
      gl_lds16(&B[(size_t)(n0 + srow)*K + k0 + scol],      &lB[buf^1][srow*32 + scol]);
      gl_lds16(&B[(size_t)(n0 + 64 + srow)*K + k0 + scol], &lB[buf^1][(64+srow)*32 + scol]);
    }
    short8 af[4], bfv[4];
    #pragma unroll
    for (int i=0;i<4;i++)
      af[i] = *(const short8*)&lA[buf][(wr + i*16 + r16)*32 + g4*8];
    #pragma unroll
    for (int j=0;j<4;j++)
      bfv[j] = *(const short8*)&lB[buf][(wc + j*16 + r16)*32 + g4*8];
    #pragma unroll
    for (int i=0;i<4;i++)
      #pragma unroll
      for (int j=0;j<4;j++)
        acc[i][j] = __builtin_amdgcn_mfma_f32_16x16x32_bf16(af[i], bfv[j], acc[i][j], 0,0,0);
    buf ^= 1;
  }

  #pragma unroll
  for (int i=0;i<4;i++){
    const int row = m0 + wr + i*16 + g4*4;
    #pragma unroll
    for (int j=0;j<4;j++){
      const int col = n0 + wc + j*16 + r16;
      #pragma unroll
      for (int r=0;r<4;r++)
        C[(size_t)(row+r)*N + col] = acc[i][j][r];
    }
  }
}

// ---------------- Flash attention (round-5, unchanged) ----------------------
__global__ __launch_bounds__(256) void attn_kernel(const u16* __restrict__ qk,
                                                   const u16* __restrict__ vt,
                                                   u16* __restrict__ y){
  __shared__ __align__(16) u16 Kl[2][64*128];
  __shared__ __align__(16) u16 Vl[2][128*64];
  __shared__ __align__(16) u16 Pl[4][32*64];

  const int tid = threadIdx.x, lane = tid & 63, wave = tid >> 6;
  const int r16 = lane & 15, g4 = lane >> 4;

  const int id = blockIdx.x;
  const int xk = id & 7,  kk = id >> 3;
  const int bh = 4*xk + (kk & 3);
  const int v5 = kk >> 2;
  const int qt = (v5 < 8) ? v5 : (23 - v5);

  const int b = bh >> 4, h = bh & 15;
  const int qcol = h*128, kcol = 2048 + h*128;
  const u16* vhead = vt + (size_t)bh * 262144;
  const float scale = 0.08838834764831845f;

  short8 qf[2][4];
  #pragma unroll
  for (int i=0;i<2;i++){
    const u16* qp = qk + (size_t)(b*T_SEQ + qt*128 + wave*32 + i*16 + r16)*4096 + qcol;
    #pragma unroll
    for (int c=0;c<4;c++) qf[i][c] = *(const short8*)&qp[g4*8 + c*32];
  }

  float mrow[2][4], lrow[2][4];
  #pragma unroll
  for (int i=0;i<2;i++)
    #pragma unroll
    for (int r=0;r<4;r++){ mrow[i][r] = -1e30f; lrow[i][r] = 0.f; }
  f32x4 o[2][8] = {};

  const int nt = 2*qt + 2;

  auto stage = [&](int sbuf, int t){
    const size_t kbase = (size_t)(b*T_SEQ + t*64)*4096 + kcol;
    #pragma unroll
    for (int c=0;c<4;c++){
      const int row0 = wave*16 + c*4;
      const int row  = row0 + g4;
      gl_lds16(&qk[kbase + (size_t)row*4096 + ((r16*8) ^ ((row&7)<<3))],
               &Kl[sbuf][row0*128]);
    }
    const int t0 = t*64;
    #pragma unroll
    for (int c=0;c<4;c++){
      const int idx = wave*4 + c;
      const int d   = idx*8 + (lane>>3);
      const int j8  = (lane&7)*8;
      gl_lds16(&vhead[(size_t)d*2048 + t0 + (j8 ^ ((d&7)<<3))],
               &Vl[sbuf][idx*512]);
    }
  };

  stage(0, 0);
  int cur = 0;

  for (int t = 0; t < nt; ++t){
    __syncthreads();
    if (t + 1 < nt) stage(cur^1, t+1);

    float smat[2][4][4];
    #pragma unroll
    for (int cc=0;cc<4;cc++){
      const int krow = cc*16 + r16;
      const int sw = (krow & 7) << 3;
      short8 kf[4];
      #pragma unroll
      for (int dc=0;dc<4;dc++)
        kf[dc] = *(const short8*)&Kl[cur][krow*128 + ((g4*8 + dc*32) ^ sw)];
      #pragma unroll
      for (int i=0;i<2;i++){
        f32x4 sv = {0.f,0.f,0.f,0.f};
        #pragma unroll
        for (int dc=0;dc<4;dc++)
          sv = __builtin_amdgcn_mfma_f32_16x16x32_bf16(qf[i][dc], kf[dc], sv, 0,0,0);
        #pragma unroll
        for (int rr=0;rr<4;rr++) smat[i][cc][rr] = sv[rr] * scale;
      }
    }
    if (t >= 2*qt){
      #pragma unroll
      for (int cc=0;cc<4;cc++){
        const int kvl = (t - 2*qt)*64 + cc*16 + r16;
        #pragma unroll
        for (int i=0;i<2;i++)
          #pragma unroll
          for (int rr=0;rr<4;rr++){
            const int qi = wave*32 + i*16 + g4*4 + rr;
            if (kvl > qi) smat[i][cc][rr] = -1e30f;
          }
      }
    }

    float corr[2][4];
    #pragma unroll
    for (int i=0;i<2;i++)
      #pragma unroll
      for (int rr=0;rr<4;rr++){
        float pm = fmaxf(fmaxf(smat[i][0][rr], smat[i][1][rr]),
                         fmaxf(smat[i][2][rr], smat[i][3][rr]));
        #pragma unroll
        for (int off=1; off<16; off<<=1) pm = fmaxf(pm, __shfl_xor(pm, off, 64));
        const float mnew = fmaxf(mrow[i][rr], pm);
        corr[i][rr] = __expf(mrow[i][rr] - mnew);
        float s0 = 0.f;
        #pragma unroll
        for (int cc=0;cc<4;cc++){
          const float p = __expf(smat[i][cc][rr] - mnew);
          smat[i][cc][rr] = p;
          s0 += p;
        }
        #pragma unroll
        for (int off=1; off<16; off<<=1) s0 += __shfl_xor(s0, off, 64);
        lrow[i][rr] = lrow[i][rr]*corr[i][rr] + s0;
        mrow[i][rr] = mnew;
      }
    #pragma unroll
    for (int i=0;i<2;i++)
      #pragma unroll
      for (int n=0;n<8;n++)
        #pragma unroll
        for (int rr=0;rr<4;rr++)
          o[i][n][rr] *= corr[i][rr];

    #pragma unroll
    for (int i=0;i<2;i++)
      #pragma unroll
      for (int cc=0;cc<4;cc++)
        #pragma unroll
        for (int rr=0;rr<4;rr++){
          const int qr = i*16 + g4*4 + rr;
          Pl[wave][qr*64 + ((cc*16 + r16) ^ ((qr&7)<<3))] = f2bf(smat[i][cc][rr]);
        }
    asm volatile("s_waitcnt lgkmcnt(0)" ::: "memory");

    short8 pf[2][2];
    #pragma unroll
    for (int i=0;i<2;i++){
      const int qr = i*16 + r16;
      const int sw = (qr & 7) << 3;
      pf[i][0] = *(const short8*)&Pl[wave][qr*64 + ((g4*8)      ^ sw)];
      pf[i][1] = *(const short8*)&Pl[wave][qr*64 + ((g4*8 + 32) ^ sw)];
    }
    #pragma unroll
    for (int n=0;n<8;n++){
      const int vr = n*16 + r16;
      const int sw = (vr & 7) << 3;
      short8 vf0 = *(const short8*)&Vl[cur][vr*64 + ((g4*8)      ^ sw)];
      short8 vf1 = *(const short8*)&Vl[cur][vr*64 + ((g4*8 + 32) ^ sw)];
      #pragma unroll
      for (int i=0;i<2;i++){
        o[i][n] = __builtin_amdgcn_mfma_f32_16x16x32_bf16(pf[i][0], vf0, o[i][n], 0,0,0);
        o[i][n] = __builtin_amdgcn_mfma_f32_16x16x32_bf16(pf[i][1], vf1, o[i][n], 0,0,0);
      }
    }
    cur ^= 1;
  }

  #pragma unroll
  for (int i=0;i<2;i++){
    const size_t yr0 = (size_t)(b*T_SEQ + qt*128 + wave*32 + i*16 + g4*4) * C_DIM + h*128;
    #pragma unroll
    for (int n=0;n<8;n++)
      #pragma unroll
      for (int rr=0;rr<4;rr++){
        const float v = o[i][n][rr] / lrow[i][rr];
        y[yr0 + (size_t)rr*C_DIM + n*16 + r16] = f2bf(v);
      }
  }
}

extern "C" void kernel_launch(void* const* d_in, const int* in_sizes, int n_in,
                              void* d_out, int out_size, void* d_ws, size_t ws_size,
                              hipStream_t stream){
  const float* x  = (const float*)d_in[0];
  const float* wa = (const float*)d_in[1];
  const float* wp = (const float*)d_in[2];
  float* out = (float*)d_out;

  u16* ws  = (u16*)d_ws;
  u16* xb  = ws;                 //  8,388,608 elems (x bf16) — reused as yb later
  u16* wab = xb  + 8388608;      // 12,582,912 elems (w_attn bf16)
  u16* wpb = wab + 12582912;     //  4,194,304 elems (w_proj bf16)
  u16* qk  = wpb + 4194304;      // 16,777,216 elems ([4096][4096] Q|K)
  u16* vt  = qk  + 16777216;     //  8,388,608 elems ([32][128][2048] V^T)
  u16* yb  = xb;                 // alias: x dead after GEMM1

  hipLaunchKernelGGL(cvt_kernel, dim3(1024), dim3(256), 0, stream, x,  xb,  8388608/4);
  hipLaunchKernelGGL(cvt_kernel, dim3(1024), dim3(256), 0, stream, wa, wab, 12582912/4);
  hipLaunchKernelGGL(cvt_kernel, dim3(1024), dim3(256), 0, stream, wp, wpb, 4194304/4);

  // qkv projection: grid 24 n-tiles(256) x 16 m-tiles(256) = 384 blocks
  hipLaunchKernelGGL((gemm256<1,u16>), dim3(24,16), dim3(512), 0, stream,
                     xb, wab, qk, vt, 4096, 6144, 2048);
  hipLaunchKernelGGL(attn_kernel,      dim3(512),  dim3(256), 0, stream,
                     qk, vt, yb);
  // out projection: 128x128 tiles, grid 16 x 32 = 512 blocks
  hipLaunchKernelGGL(gemm128,          dim3(16,32), dim3(256), 0, stream,
                     yb, wpb, out, 4096, 2048, 2048);
}